// Round 2
// baseline (447.000 us; speedup 1.0000x reference)
//
#include <hip/hip_runtime.h>
#include <hip/hip_bf16.h>
#include <stdint.h>

// Problem dims (fixed by reference): B=64, T=512, H=1024, A=300
#define B_DIM 64
#define T_DIM 512
#define H_DIM 1024
#define M_DIM (B_DIM * T_DIM)  // 32768 rows of the big GEMM

typedef __bf16 bf16x8 __attribute__((ext_vector_type(8)));
typedef float f32x4 __attribute__((ext_vector_type(4)));

__device__ __forceinline__ float tanh_fast(float x) {
  // tanh(x) = 1 - 2/(exp(2x)+1); exact at +-inf saturation
  float e = __expf(2.0f * x);
  return 1.0f - 2.0f / (e + 1.0f);
}

// async global->LDS, 16B per lane. LDS dest must be wave-uniform base + lane*16.
__device__ __forceinline__ void async_cp16(const void* gp, void* lp) {
  __builtin_amdgcn_global_load_lds(
      reinterpret_cast<const __attribute__((address_space(1))) uint32_t*>(
          reinterpret_cast<uintptr_t>(gp)),
      reinterpret_cast<__attribute__((address_space(3))) uint32_t*>(
          reinterpret_cast<uintptr_t>(lp)),
      16, 0, 0);
}

// ---------------- fp32 -> bf16 conversion (vectorized) ----------------
__global__ void cvt_kernel(const float* __restrict__ src, __bf16* __restrict__ dst, int n4) {
  int i = blockIdx.x * 256 + threadIdx.x;
  if (i >= n4) return;
  float4 v = reinterpret_cast<const float4*>(src)[i];
  union { __bf16 b[4]; uint2 u; } o;
  o.b[0] = (__bf16)v.x; o.b[1] = (__bf16)v.y; o.b[2] = (__bf16)v.z; o.b[3] = (__bf16)v.w;
  reinterpret_cast<uint2*>(dst)[i] = o.u;
}

// ---------------- fused GEMM + tanh + dot(w_w) -> scores ----------------
// A: [M,K] bf16 (hidden), Bm: [N,K] bf16 (W_h, row n = output feature)
// scores[m] += sum_n tanh(A@Bm^T + b_h)[m,n] * w_w[n]   (scores pre-zeroed)
#define GM_BK 32
__global__ __launch_bounds__(256) void gemm_scores_kernel(
    const __bf16* __restrict__ A, const __bf16* __restrict__ Bm,
    const float* __restrict__ bh, const float* __restrict__ ww,
    float* __restrict__ scores, int K) {
  __shared__ __attribute__((aligned(16))) __bf16 lA[128 * GM_BK];
  __shared__ __attribute__((aligned(16))) __bf16 lB[128 * GM_BK];

  const int tid = threadIdx.x;
  const int m0 = blockIdx.y * 128;
  const int n0 = blockIdx.x * 128;

  const int wv = tid >> 6;
  const int lane = tid & 63;
  const int wm = wv & 1, wn = wv >> 1;           // 2x2 waves, each 64x64
  const int r16 = lane & 15, quad = lane >> 4;

  f32x4 acc[4][4] = {};

  // staging: 256 threads x 16B x 2 per tile (128x32 bf16 = 8KB)
  const int srow = tid >> 2;
  const int scol = (tid & 3) * 8;
  const __bf16* gA0 = A + (size_t)(m0 + srow) * K + scol;
  const __bf16* gA1 = A + (size_t)(m0 + 64 + srow) * K + scol;
  const __bf16* gB0 = Bm + (size_t)(n0 + srow) * K + scol;
  const __bf16* gB1 = Bm + (size_t)(n0 + 64 + srow) * K + scol;
  __bf16* lA0 = &lA[tid * 8];
  __bf16* lA1 = &lA[(256 + tid) * 8];
  __bf16* lB0 = &lB[tid * 8];
  __bf16* lB1 = &lB[(256 + tid) * 8];

  const __bf16* pa = &lA[(wm * 64 + r16) * GM_BK + quad * 8];
  const __bf16* pb = &lB[(wn * 64 + r16) * GM_BK + quad * 8];

  for (int k0 = 0; k0 < K; k0 += GM_BK) {
    async_cp16(gA0 + k0, lA0);
    async_cp16(gA1 + k0, lA1);
    async_cp16(gB0 + k0, lB0);
    async_cp16(gB1 + k0, lB1);
    __syncthreads();  // compiler drains vmcnt before barrier
    bf16x8 af[4], bfr[4];
#pragma unroll
    for (int i = 0; i < 4; ++i) af[i] = *reinterpret_cast<const bf16x8*>(pa + i * 16 * GM_BK);
#pragma unroll
    for (int i = 0; i < 4; ++i) bfr[i] = *reinterpret_cast<const bf16x8*>(pb + i * 16 * GM_BK);
#pragma unroll
    for (int mi = 0; mi < 4; ++mi)
#pragma unroll
      for (int ni = 0; ni < 4; ++ni)
        acc[mi][ni] = __builtin_amdgcn_mfma_f32_16x16x32_bf16(af[mi], bfr[ni], acc[mi][ni], 0, 0, 0);
    __syncthreads();
  }

  // epilogue: C/D layout col=lane&15, row=quad*4+reg (m89-verified)
  float bhv[4], wwv[4];
#pragma unroll
  for (int ni = 0; ni < 4; ++ni) {
    int n = n0 + wn * 64 + ni * 16 + r16;
    bhv[ni] = bh[n];
    wwv[ni] = ww[n];
  }
#pragma unroll
  for (int mi = 0; mi < 4; ++mi) {
#pragma unroll
    for (int rg = 0; rg < 4; ++rg) {
      float s = 0.f;
#pragma unroll
      for (int ni = 0; ni < 4; ++ni)
        s += tanh_fast(acc[mi][ni][rg] + bhv[ni]) * wwv[ni];
      s += __shfl_xor(s, 1, 16);
      s += __shfl_xor(s, 2, 16);
      s += __shfl_xor(s, 4, 16);
      s += __shfl_xor(s, 8, 16);
      if (r16 == 0) {
        int m = m0 + wm * 64 + mi * 16 + quad * 4 + rg;
        atomicAdd(&scores[m], s);
      }
    }
  }
}

// ---------------- softmax over T per batch ----------------
__global__ void softmax_kernel(const float* __restrict__ scores, float* __restrict__ alpha) {
  __shared__ float wred[4], wsum[4];
  const int b = blockIdx.x, tid = threadIdx.x;
  const int wv = tid >> 6, lane = tid & 63;
  float v0 = scores[b * T_DIM + tid];
  float v1 = scores[b * T_DIM + 256 + tid];
  float mx = fmaxf(v0, v1);
#pragma unroll
  for (int off = 1; off < 64; off <<= 1) mx = fmaxf(mx, __shfl_xor(mx, off, 64));
  if (lane == 0) wred[wv] = mx;
  __syncthreads();
  mx = fmaxf(fmaxf(wred[0], wred[1]), fmaxf(wred[2], wred[3]));
  float e0 = __expf(v0 - mx), e1 = __expf(v1 - mx);
  float s = e0 + e1;
#pragma unroll
  for (int off = 1; off < 64; off <<= 1) s += __shfl_xor(s, off, 64);
  if (lane == 0) wsum[wv] = s;
  __syncthreads();
  s = wsum[0] + wsum[1] + wsum[2] + wsum[3];
  float inv = 1.0f / s;
  alpha[b * T_DIM + tid] = e0 * inv;
  alpha[b * T_DIM + 256 + tid] = e1 * inv;
}

// ---------------- r[b,h] = sum_t alpha[b,t] * hidden[b,t,h] ----------------
__global__ void weighted_sum_kernel(const float* __restrict__ hidden,
                                    const float* __restrict__ alpha,
                                    float* __restrict__ r) {
  __shared__ float al[T_DIM];
  const int b = blockIdx.y, tid = threadIdx.x;
  al[tid] = alpha[b * T_DIM + tid];
  al[tid + 256] = alpha[b * T_DIM + 256 + tid];
  __syncthreads();
  const int h = blockIdx.x * 256 + tid;
  const float* hp = hidden + (size_t)b * T_DIM * H_DIM + h;
  float acc = 0.f;
#pragma unroll 8
  for (int t = 0; t < T_DIM; ++t) acc += al[t] * hp[(size_t)t * H_DIM];
  r[b * H_DIM + h] = acc;
}

// ---------------- dst[i,h] = bias[h] + src_row_i . W[h,:] ----------------
__global__ void rowvec_matT_kernel(const float* __restrict__ src, size_t src_stride,
                                   const float* __restrict__ W, const float* __restrict__ bias,
                                   float* __restrict__ dst) {
  __shared__ float sv[H_DIM];
  const int i = blockIdx.y, tid = threadIdx.x;
  reinterpret_cast<float4*>(sv)[tid] =
      reinterpret_cast<const float4*>(src + (size_t)i * src_stride)[tid];
  __syncthreads();
  const int h = blockIdx.x * 256 + tid;
  const float* wr = W + (size_t)h * H_DIM;
  float acc = bias[h];
#pragma unroll 4
  for (int k = 0; k < H_DIM; k += 4) {
    float4 w4 = *reinterpret_cast<const float4*>(wr + k);
    float4 s4 = *reinterpret_cast<const float4*>(sv + k);
    acc += w4.x * s4.x + w4.y * s4.y + w4.z * s4.z + w4.w * s4.w;
  }
  dst[(size_t)i * H_DIM + h] = acc;
}

// ---------------- out[i,j,h] = tanh(rp[i,h] + xq[j,h])  [B,B,H] quirk ----------------
__global__ void final_kernel(const float* __restrict__ rp, const float* __restrict__ xq,
                             float* __restrict__ out) {
  int idx = blockIdx.x * 256 + threadIdx.x;  // one float4 each
  int e = idx * 4;
  int i = e >> 16;          // / (B*H) = 65536
  int j = (e >> 10) & 63;   // / H % B
  int h = e & 1023;
  float4 a = *reinterpret_cast<const float4*>(&rp[i * H_DIM + h]);
  float4 b = *reinterpret_cast<const float4*>(&xq[j * H_DIM + h]);
  float4 o;
  o.x = tanh_fast(a.x + b.x);
  o.y = tanh_fast(a.y + b.y);
  o.z = tanh_fast(a.z + b.z);
  o.w = tanh_fast(a.w + b.w);
  *reinterpret_cast<float4*>(&out[e]) = o;
}

extern "C" void kernel_launch(void* const* d_in, const int* in_sizes, int n_in,
                              void* d_out, int out_size, void* d_ws, size_t ws_size,
                              hipStream_t stream) {
  const float* hidden = (const float*)d_in[0];
  // aspect (1), W_v (4), b_v (5), w_b (7) cancel under softmax -> unused
  const float* W_h = (const float*)d_in[2];
  const float* b_h = (const float*)d_in[3];
  const float* w_w = (const float*)d_in[6];  // use first H entries
  const float* W_p = (const float*)d_in[8];
  const float* b_p = (const float*)d_in[9];
  const float* W_x = (const float*)d_in[10];
  const float* b_x = (const float*)d_in[11];
  float* out = (float*)d_out;

  char* ws = (char*)d_ws;
  __bf16* hidBf = (__bf16*)ws;                  // 64 MB
  __bf16* whBf = (__bf16*)(ws + 67108864);      // 2 MB
  float* scores = (float*)(ws + 69206016);      // 128 KB
  float* alpha = (float*)(ws + 69337088);       // 128 KB
  float* r = (float*)(ws + 69468160);           // 256 KB
  float* rp = (float*)(ws + 69730304);          // 256 KB
  float* xq = (float*)(ws + 69992448);          // 256 KB

  // 1) convert hidden + W_h to bf16
  cvt_kernel<<<(M_DIM * H_DIM / 4) / 256, 256, 0, stream>>>(hidden, hidBf, M_DIM * H_DIM / 4);
  cvt_kernel<<<(H_DIM * H_DIM / 4) / 256, 256, 0, stream>>>(W_h, whBf, H_DIM * H_DIM / 4);

  // 2) scores (zero first; ws is poisoned every call)
  hipMemsetAsync(scores, 0, M_DIM * sizeof(float), stream);
  gemm_scores_kernel<<<dim3(H_DIM / 128, M_DIM / 128), 256, 0, stream>>>(
      hidBf, whBf, b_h, w_w, scores, H_DIM);

  // 3) softmax over T
  softmax_kernel<<<B_DIM, 256, 0, stream>>>(scores, alpha);

  // 4) r = alpha^T . hidden
  weighted_sum_kernel<<<dim3(H_DIM / 256, B_DIM), 256, 0, stream>>>(hidden, alpha, r);

  // 5) rp = r @ W_p^T + b_p ; xq = hidden[:,-1,:] @ W_x^T + b_x
  rowvec_matT_kernel<<<dim3(H_DIM / 256, B_DIM), 256, 0, stream>>>(r, (size_t)H_DIM, W_p, b_p, rp);
  rowvec_matT_kernel<<<dim3(H_DIM / 256, B_DIM), 256, 0, stream>>>(
      hidden + (size_t)(T_DIM - 1) * H_DIM, (size_t)T_DIM * H_DIM, W_x, b_x, xq);

  // 6) out[i,j,h] = tanh(rp[i,h] + xq[j,h])
  final_kernel<<<(B_DIM * B_DIM * H_DIM / 4) / 256, 256, 0, stream>>>(rp, xq, out);
}

// Round 3
// 424.096 us; speedup vs baseline: 1.0540x; 1.0540x over previous
//
#include <hip/hip_runtime.h>
#include <hip/hip_bf16.h>
#include <stdint.h>

// Problem dims (fixed by reference): B=64, T=512, H=1024, A=300
#define B_DIM 64
#define T_DIM 512
#define H_DIM 1024
#define M_DIM (B_DIM * T_DIM)  // 32768 rows of the big GEMM

typedef __bf16 bf16x8 __attribute__((ext_vector_type(8)));
typedef float f32x4 __attribute__((ext_vector_type(4)));

__device__ __forceinline__ float tanh_fast(float x) {
  float e = __expf(2.0f * x);
  return 1.0f - 2.0f / (e + 1.0f);
}

// async global->LDS, 16B per lane. LDS dest must be wave-uniform base + lane*16.
__device__ __forceinline__ void async_cp16(const void* gp, void* lp) {
  __builtin_amdgcn_global_load_lds(
      reinterpret_cast<const __attribute__((address_space(1))) uint32_t*>(
          reinterpret_cast<uintptr_t>(gp)),
      reinterpret_cast<__attribute__((address_space(3))) uint32_t*>(
          reinterpret_cast<uintptr_t>(lp)),
      16, 0, 0);
}

// ---------------- fp32 -> bf16 conversion (vectorized) ----------------
__global__ void cvt_kernel(const float* __restrict__ src, __bf16* __restrict__ dst, int n4) {
  int i = blockIdx.x * 256 + threadIdx.x;
  if (i >= n4) return;
  float4 v = reinterpret_cast<const float4*>(src)[i];
  union { __bf16 b[4]; uint2 u; } o;
  o.b[0] = (__bf16)v.x; o.b[1] = (__bf16)v.y; o.b[2] = (__bf16)v.z; o.b[3] = (__bf16)v.w;
  reinterpret_cast<uint2*>(dst)[i] = o.u;
}

// ---------------- fused GEMM + tanh + dot(w_w) -> scores ----------------
// A: [M,K] bf16 (hidden), Bm: [N,K] bf16 (W_h). scores[m] += sum_n tanh(..)*ww[n]
// LDS layout: 16B chunks; chunk (row, p) holds k-chunk kc = p ^ ((row>>1)&7).
// Row stride = 64 bf16 = 128 B (bank-aligned); swizzle spreads quad reads over
// 8 distinct 4-bank groups -> 2-way aliasing only (free, m136).
#define GM_BK 64
__global__ __launch_bounds__(256) void gemm_scores_kernel(
    const __bf16* __restrict__ A, const __bf16* __restrict__ Bm,
    const float* __restrict__ bh, const float* __restrict__ ww,
    float* __restrict__ scores, int K) {
  __shared__ __attribute__((aligned(16))) __bf16 lA[128 * GM_BK];  // 16 KB
  __shared__ __attribute__((aligned(16))) __bf16 lB[128 * GM_BK];  // 16 KB

  const int tid = threadIdx.x;
  const int m0 = blockIdx.y * 128;
  const int n0 = blockIdx.x * 128;

  const int wv = tid >> 6;
  const int lane = tid & 63;
  const int wm = wv & 1, wn = wv >> 1;           // 2x2 waves, each 64x64
  const int r16 = lane & 15, quad = lane >> 4;

  f32x4 acc[4][4] = {};

  // staging: 4 chunks of A + 4 of B per thread per iter (1024 chunks/tile)
  const __bf16* gA[4]; const __bf16* gB[4];
  __bf16* lAd[4]; __bf16* lBd[4];
#pragma unroll
  for (int j = 0; j < 4; ++j) {
    int c = j * 256 + tid;
    int row = c >> 3;
    int p = c & 7;
    int kc = p ^ ((row >> 1) & 7);            // global k-chunk stored at position p
    gA[j] = A + (size_t)(m0 + row) * K + kc * 8;
    gB[j] = Bm + (size_t)(n0 + row) * K + kc * 8;
    lAd[j] = &lA[c * 8];
    lBd[j] = &lB[c * 8];
  }

  // fragment read pointers; s(row) = (row>>1)&7 == r16>>1 for our rows
  const int sw = r16 >> 1;
  const __bf16* pa[2]; const __bf16* pb[2];
#pragma unroll
  for (int kk = 0; kk < 2; ++kk) {
    pa[kk] = &lA[(wm * 64 + r16) * GM_BK + ((kk * 4 + quad) ^ sw) * 8];
    pb[kk] = &lB[(wn * 64 + r16) * GM_BK + ((kk * 4 + quad) ^ sw) * 8];
  }

  for (int k0 = 0; k0 < K; k0 += GM_BK) {
#pragma unroll
    for (int j = 0; j < 4; ++j) async_cp16(gA[j] + k0, lAd[j]);
#pragma unroll
    for (int j = 0; j < 4; ++j) async_cp16(gB[j] + k0, lBd[j]);
    __syncthreads();
#pragma unroll
    for (int kk = 0; kk < 2; ++kk) {
      bf16x8 af[4], bfr[4];
#pragma unroll
      for (int i = 0; i < 4; ++i) af[i] = *reinterpret_cast<const bf16x8*>(pa[kk] + i * 16 * GM_BK);
#pragma unroll
      for (int i = 0; i < 4; ++i) bfr[i] = *reinterpret_cast<const bf16x8*>(pb[kk] + i * 16 * GM_BK);
#pragma unroll
      for (int mi = 0; mi < 4; ++mi)
#pragma unroll
        for (int ni = 0; ni < 4; ++ni)
          acc[mi][ni] = __builtin_amdgcn_mfma_f32_16x16x32_bf16(af[mi], bfr[ni], acc[mi][ni], 0, 0, 0);
    }
    __syncthreads();
  }

  // epilogue: C/D layout col=lane&15, row=quad*4+reg (m89-verified)
  float bhv[4], wwv[4];
#pragma unroll
  for (int ni = 0; ni < 4; ++ni) {
    int n = n0 + wn * 64 + ni * 16 + r16;
    bhv[ni] = bh[n];
    wwv[ni] = ww[n];
  }
#pragma unroll
  for (int mi = 0; mi < 4; ++mi) {
#pragma unroll
    for (int rg = 0; rg < 4; ++rg) {
      float s = 0.f;
#pragma unroll
      for (int ni = 0; ni < 4; ++ni)
        s += tanh_fast(acc[mi][ni][rg] + bhv[ni]) * wwv[ni];
      s += __shfl_xor(s, 1, 16);
      s += __shfl_xor(s, 2, 16);
      s += __shfl_xor(s, 4, 16);
      s += __shfl_xor(s, 8, 16);
      if (r16 == 0) {
        int m = m0 + wm * 64 + mi * 16 + quad * 4 + rg;
        atomicAdd(&scores[m], s);
      }
    }
  }
}

// ---------------- softmax over T per batch ----------------
__global__ void softmax_kernel(const float* __restrict__ scores, float* __restrict__ alpha) {
  __shared__ float wred[4], wsum[4];
  const int b = blockIdx.x, tid = threadIdx.x;
  const int wv = tid >> 6, lane = tid & 63;
  float v0 = scores[b * T_DIM + tid];
  float v1 = scores[b * T_DIM + 256 + tid];
  float mx = fmaxf(v0, v1);
#pragma unroll
  for (int off = 1; off < 64; off <<= 1) mx = fmaxf(mx, __shfl_xor(mx, off, 64));
  if (lane == 0) wred[wv] = mx;
  __syncthreads();
  mx = fmaxf(fmaxf(wred[0], wred[1]), fmaxf(wred[2], wred[3]));
  float e0 = __expf(v0 - mx), e1 = __expf(v1 - mx);
  float s = e0 + e1;
#pragma unroll
  for (int off = 1; off < 64; off <<= 1) s += __shfl_xor(s, off, 64);
  if (lane == 0) wsum[wv] = s;
  __syncthreads();
  s = wsum[0] + wsum[1] + wsum[2] + wsum[3];
  float inv = 1.0f / s;
  alpha[b * T_DIM + tid] = e0 * inv;
  alpha[b * T_DIM + 256 + tid] = e1 * inv;
}

// ---------------- r[b,h] += sum_{t in chunk} alpha[b,t]*hidden[b,t,h] ----------------
// grid (8, B): 512 blocks; r pre-zeroed; float4 coalesced; 8-way atomic contention.
__global__ void weighted_sum_kernel(const float* __restrict__ hidden,
                                    const float* __restrict__ alpha,
                                    float* __restrict__ r) {
  __shared__ float al[64];
  const int b = blockIdx.y, tc = blockIdx.x, tid = threadIdx.x;
  if (tid < 64) al[tid] = alpha[b * T_DIM + tc * 64 + tid];
  __syncthreads();
  const float* hp = hidden + (size_t)b * T_DIM * H_DIM + (size_t)tc * 64 * H_DIM + tid * 4;
  float4 acc = make_float4(0.f, 0.f, 0.f, 0.f);
#pragma unroll 8
  for (int t = 0; t < 64; ++t) {
    float a = al[t];
    float4 v = *reinterpret_cast<const float4*>(hp + (size_t)t * H_DIM);
    acc.x += a * v.x; acc.y += a * v.y; acc.z += a * v.z; acc.w += a * v.w;
  }
  float* rp = r + b * H_DIM + tid * 4;
  atomicAdd(rp + 0, acc.x);
  atomicAdd(rp + 1, acc.y);
  atomicAdd(rp + 2, acc.z);
  atomicAdd(rp + 3, acc.w);
}

// ---------------- dst[i,h] = bias[h] + src_row_i . W[h,:] ----------------
// grid (H/64, B) = 1024 blocks; 4 lanes split K per output h; shfl-reduce.
__global__ void rowvec_matT_kernel(const float* __restrict__ src, size_t src_stride,
                                   const float* __restrict__ W, const float* __restrict__ bias,
                                   float* __restrict__ dst) {
  __shared__ float sv[H_DIM];
  const int i = blockIdx.y, h0 = blockIdx.x * 64, tid = threadIdx.x;
  reinterpret_cast<float4*>(sv)[tid] =
      reinterpret_cast<const float4*>(src + (size_t)i * src_stride)[tid];
  __syncthreads();
  const int hl = tid >> 2;        // 0..63
  const int kq = tid & 3;         // K quarter
  const float* wr = W + (size_t)(h0 + hl) * H_DIM + kq * 256;
  const float* svp = sv + kq * 256;
  float acc = 0.f;
#pragma unroll 4
  for (int k = 0; k < 256; k += 4) {
    float4 w4 = *reinterpret_cast<const float4*>(wr + k);
    float4 s4 = *reinterpret_cast<const float4*>(svp + k);
    acc += w4.x * s4.x + w4.y * s4.y + w4.z * s4.z + w4.w * s4.w;
  }
  acc += __shfl_xor(acc, 1, 4);
  acc += __shfl_xor(acc, 2, 4);
  if (kq == 0) dst[(size_t)i * H_DIM + h0 + hl] = acc + bias[h0 + hl];
}

// ---------------- out[i,j,h] = tanh(rp[i,h] + xq[j,h])  [B,B,H] quirk ----------------
__global__ void final_kernel(const float* __restrict__ rp, const float* __restrict__ xq,
                             float* __restrict__ out) {
  int idx = blockIdx.x * 256 + threadIdx.x;  // one float4 each
  int e = idx * 4;
  int i = e >> 16;          // / (B*H) = 65536
  int j = (e >> 10) & 63;   // / H % B
  int h = e & 1023;
  float4 a = *reinterpret_cast<const float4*>(&rp[i * H_DIM + h]);
  float4 b = *reinterpret_cast<const float4*>(&xq[j * H_DIM + h]);
  float4 o;
  o.x = tanh_fast(a.x + b.x);
  o.y = tanh_fast(a.y + b.y);
  o.z = tanh_fast(a.z + b.z);
  o.w = tanh_fast(a.w + b.w);
  *reinterpret_cast<float4*>(&out[e]) = o;
}

extern "C" void kernel_launch(void* const* d_in, const int* in_sizes, int n_in,
                              void* d_out, int out_size, void* d_ws, size_t ws_size,
                              hipStream_t stream) {
  const float* hidden = (const float*)d_in[0];
  // aspect (1), W_v (4), b_v (5), w_b (7) cancel under softmax -> unused
  const float* W_h = (const float*)d_in[2];
  const float* b_h = (const float*)d_in[3];
  const float* w_w = (const float*)d_in[6];  // use first H entries
  const float* W_p = (const float*)d_in[8];
  const float* b_p = (const float*)d_in[9];
  const float* W_x = (const float*)d_in[10];
  const float* b_x = (const float*)d_in[11];
  float* out = (float*)d_out;

  char* ws = (char*)d_ws;
  __bf16* hidBf = (__bf16*)ws;                  // 64 MB
  __bf16* whBf = (__bf16*)(ws + 67108864);      // 2 MB
  float* scores = (float*)(ws + 69206016);      // 128 KB
  float* alpha = (float*)(ws + 69337088);       // 128 KB
  float* r = (float*)(ws + 69468160);           // 256 KB
  float* rp = (float*)(ws + 69730304);          // 256 KB
  float* xq = (float*)(ws + 69992448);          // 256 KB

  // 1) convert hidden + W_h to bf16
  cvt_kernel<<<(M_DIM * H_DIM / 4) / 256, 256, 0, stream>>>(hidden, hidBf, M_DIM * H_DIM / 4);
  cvt_kernel<<<(H_DIM * H_DIM / 4) / 256, 256, 0, stream>>>(W_h, whBf, H_DIM * H_DIM / 4);

  // 2) scores (zero first; ws is poisoned every call)
  hipMemsetAsync(scores, 0, M_DIM * sizeof(float), stream);
  hipMemsetAsync(r, 0, B_DIM * H_DIM * sizeof(float), stream);
  gemm_scores_kernel<<<dim3(H_DIM / 128, M_DIM / 128), 256, 0, stream>>>(
      hidBf, whBf, b_h, w_w, scores, H_DIM);

  // 3) softmax over T
  softmax_kernel<<<B_DIM, 256, 0, stream>>>(scores, alpha);

  // 4) r = alpha^T . hidden  (T split 8-way)
  weighted_sum_kernel<<<dim3(8, B_DIM), 256, 0, stream>>>(hidden, alpha, r);

  // 5) rp = r @ W_p^T + b_p ; xq = hidden[:,-1,:] @ W_x^T + b_x
  rowvec_matT_kernel<<<dim3(H_DIM / 64, B_DIM), 256, 0, stream>>>(r, (size_t)H_DIM, W_p, b_p, rp);
  rowvec_matT_kernel<<<dim3(H_DIM / 64, B_DIM), 256, 0, stream>>>(
      hidden + (size_t)(T_DIM - 1) * H_DIM, (size_t)T_DIM * H_DIM, W_x, b_x, xq);

  // 6) out[i,j,h] = tanh(rp[i,h] + xq[j,h])
  final_kernel<<<(B_DIM * B_DIM * H_DIM / 4) / 256, 256, 0, stream>>>(rp, xq, out);
}